// Round 5
// baseline (290.224 us; speedup 1.0000x reference)
//
#include <hip/hip_runtime.h>

#define NN   50000
#define NE   800000
#define HID  128
#define OUTD 40
#define NBLK 196  // ceil(NN/256)

typedef float f32x4  __attribute__((ext_vector_type(4)));
typedef int   i32x4  __attribute__((ext_vector_type(4)));
typedef short bf16x8 __attribute__((ext_vector_type(8)));

// ---------- helpers ----------
__device__ __forceinline__ f32x4 mfma(bf16x8 a, bf16x8 b, f32x4 c) {
  return __builtin_amdgcn_mfma_f32_16x16x32_bf16(a, b, c, 0, 0, 0);
}
__device__ __forceinline__ unsigned short f2bf(float f) {
  unsigned u = __builtin_bit_cast(unsigned, f);
  u += 0x7fffu + ((u >> 16) & 1u);
  return (unsigned short)(u >> 16);
}
__device__ __forceinline__ unsigned pack2(float lo, float hi) {
  return (unsigned)f2bf(lo) | ((unsigned)f2bf(hi) << 16);
}
__device__ __forceinline__ float bflo(unsigned v){ return __builtin_bit_cast(float, v << 16); }
__device__ __forceinline__ float bfhi(unsigned v){ return __builtin_bit_cast(float, v & 0xffff0000u); }
__device__ __forceinline__ void acc8(float* a, uint4 v) {
  a[0] += bflo(v.x); a[1] += bfhi(v.x);
  a[2] += bflo(v.y); a[3] += bfhi(v.y);
  a[4] += bflo(v.z); a[5] += bfhi(v.z);
  a[6] += bflo(v.w); a[7] += bfhi(v.w);
}

// ---------- CSR build ----------
// k_deg: count in-degree AND record each edge's rank within its dst bucket.
__global__ void k_deg(const int* __restrict__ dst, int* __restrict__ deg,
                      int* __restrict__ pos) {
  int i = blockIdx.x * blockDim.x + threadIdx.x;
  if (i < NE) pos[i] = atomicAdd(&deg[dst[i]], 1);
}

__global__ void k_blocksum(const int* __restrict__ deg, int* __restrict__ bsum) {
  __shared__ int s[256];
  int t = threadIdx.x, i = blockIdx.x * 256 + t;
  s[t] = (i < NN) ? deg[i] : 0;
  __syncthreads();
  for (int o = 128; o > 0; o >>= 1) { if (t < o) s[t] += s[t + o]; __syncthreads(); }
  if (t == 0) bsum[blockIdx.x] = s[0];
}

__global__ void k_scanb(const int* __restrict__ bsum, int* __restrict__ bexcl) {
  __shared__ int s[256];
  int t = threadIdx.x;
  int v = (t < NBLK) ? bsum[t] : 0;
  s[t] = v; __syncthreads();
  for (int o = 1; o < 256; o <<= 1) {
    int x = (t >= o) ? s[t - o] : 0;
    __syncthreads(); s[t] += x; __syncthreads();
  }
  bexcl[t] = s[t] - v;  // exclusive
}

__global__ void k_scan3(const int* __restrict__ deg, const int* __restrict__ bexcl,
                        int* __restrict__ offs, float* __restrict__ dinv) {
  __shared__ int s[256];
  int t = threadIdx.x, i = blockIdx.x * 256 + t;
  int v = (i < NN) ? deg[i] : 0;
  s[t] = v; __syncthreads();
  for (int o = 1; o < 256; o <<= 1) {
    int x = (t >= o) ? s[t - o] : 0;
    __syncthreads(); s[t] += x; __syncthreads();
  }
  int off = bexcl[blockIdx.x] + s[t] - v;
  if (i < NN) {
    offs[i] = off;
    dinv[i] = 1.0f / (float)(v > 0 ? v : 1);
  }
  if (i == 0) offs[NN] = NE;
}

// no atomics: position precomputed in k_deg
__global__ void k_fill(const int* __restrict__ src, const int* __restrict__ dst,
                       const int* __restrict__ pos, const int* __restrict__ offs,
                       int* __restrict__ csr) {
  int i = blockIdx.x * blockDim.x + threadIdx.x;
  if (i < NE) {
    csr[offs[dst[i]] + pos[i]] = src[i];
  }
}

// ---------- weight prep: transpose + bf16 cast into ws ----------
// wt layout: m=0 WtIn, m=1..3 WtL[i], m=4..6 WtR[i], m=7 WtC1, then WtC2 [48][128]
__global__ void k_prep(const float* __restrict__ Win, const float* __restrict__ Wl,
                       const float* __restrict__ Wr, const float* __restrict__ Wc1,
                       const float* __restrict__ Wc2, unsigned short* __restrict__ wt) {
  int idx = blockIdx.x * 256 + threadIdx.x;
  const int NMAIN = 8 * 16384;
  if (idx >= NMAIN + 48 * 128) return;
  float v;
  if (idx < NMAIN) {
    int m = idx >> 14, rem = idx & 16383;
    int n = rem >> 7, k = rem & 127;
    const float* s;
    if (m == 0) s = Win;
    else if (m <= 3) s = Wl + (m - 1) * 16384;
    else if (m <= 6) s = Wr + (m - 4) * 16384;
    else s = Wc1;
    v = s[k * 128 + n];
  } else {
    int rem = idx - NMAIN;
    int n = rem >> 7, k = rem & 127;
    v = (n < OUTD) ? Wc2[k * OUTD + n] : 0.f;
  }
  wt[idx] = f2bf(v);
}

// ---------- aggregation: quarter-wave per row (16B/lane), 16 rows/iter ----------
// One VMEM instruction fetches 4 rows (16 lanes x 16B = one 256B row per quarter).
// Lane holds 8 fp32 column accumulators x 4 banks (ILP); cross-quarter partials
// folded with __shfl_xor(16|32); quarter 0 stores the row as one uint4.
__global__ __launch_bounds__(256) void k_agg(const unsigned short* __restrict__ h,
                                             const int* __restrict__ csr,
                                             const int* __restrict__ offs,
                                             const float* __restrict__ dinv,
                                             unsigned short* __restrict__ agg) {
  const int lane = threadIdx.x & 63;
  const int l15 = lane & 15;
  const int q = lane >> 4;  // quarter 0..3
  int gw = (blockIdx.x * blockDim.x + threadIdx.x) >> 6;
  int nw = (gridDim.x * blockDim.x) >> 6;
  const uint4* h4 = (const uint4*)h;  // row stride = 16 uint4 (256B)
  uint4* ag4 = (uint4*)agg;
  for (int n = gw; n < NN; n += nw) {
    int s = offs[n], e = offs[n + 1];
    float A0[8], A1[8], A2[8], A3[8];
#pragma unroll
    for (int j = 0; j < 8; j++) { A0[j] = 0.f; A1[j] = 0.f; A2[j] = 0.f; A3[j] = 0.f; }
    int k = s;
    for (; k + 16 <= e; k += 16) {
      int r0 = csr[k + 0 + q], r1 = csr[k + 4 + q];
      int r2 = csr[k + 8 + q], r3 = csr[k + 12 + q];
      uint4 v0 = h4[r0 * 16 + l15];
      uint4 v1 = h4[r1 * 16 + l15];
      uint4 v2 = h4[r2 * 16 + l15];
      uint4 v3 = h4[r3 * 16 + l15];
      acc8(A0, v0); acc8(A1, v1); acc8(A2, v2); acc8(A3, v3);
    }
    for (; k < e; k += 4) {
      if (k + q < e) {
        int r = csr[k + q];
        uint4 v = h4[r * 16 + l15];
        acc8(A0, v);
      }
    }
    float c[8];
#pragma unroll
    for (int j = 0; j < 8; j++) c[j] = (A0[j] + A1[j]) + (A2[j] + A3[j]);
#pragma unroll
    for (int j = 0; j < 8; j++) {
      c[j] += __shfl_xor(c[j], 16);
      c[j] += __shfl_xor(c[j], 32);
    }
    if (q == 0) {
      float di = dinv[n];
      uint4 o;
      o.x = pack2(c[0] * di, c[1] * di);
      o.y = pack2(c[2] * di, c[3] * di);
      o.z = pack2(c[4] * di, c[5] * di);
      o.w = pack2(c[6] * di, c[7] * di);
      ag4[n * 16 + l15] = o;
    }
  }
}

// ---------- GEMM: h0 = x @ W_in + b_in (x fp32, out bf16) ----------
__global__ __launch_bounds__(256) void k_lin_in(const float* __restrict__ x,
                                                const unsigned short* __restrict__ Wt,
                                                const float* __restrict__ bias,
                                                unsigned short* __restrict__ hout) {
  const int lane = threadIdx.x & 63, w = threadIdx.x >> 6;
  const int wr = w >> 1, wc = w & 1;
  const int r15 = lane & 15, khi = lane >> 4;
  const int mbase = blockIdx.x * 128 + wr * 64, nbase = wc * 64;
  f32x4 acc[4][4] = {};
#pragma unroll
  for (int ks = 0; ks < 4; ++ks) {
    const int kk = ks * 32 + khi * 8;
    bf16x8 af[4], bq[4];
#pragma unroll
    for (int i = 0; i < 4; i++) {
      int row = mbase + i * 16 + r15; row = row < NN ? row : NN - 1;
      const f32x4* p = (const f32x4*)(x + row * HID + kk);
      f32x4 lo = p[0], hi = p[1];
      i32x4 t;
      t[0] = pack2(lo[0], lo[1]); t[1] = pack2(lo[2], lo[3]);
      t[2] = pack2(hi[0], hi[1]); t[3] = pack2(hi[2], hi[3]);
      af[i] = __builtin_bit_cast(bf16x8, t);
    }
#pragma unroll
    for (int j = 0; j < 4; j++) {
      int col = nbase + j * 16 + r15;
      bq[j] = *(const bf16x8*)(Wt + col * HID + kk);
    }
#pragma unroll
    for (int i = 0; i < 4; i++)
#pragma unroll
      for (int j = 0; j < 4; j++) acc[i][j] = mfma(af[i], bq[j], acc[i][j]);
  }
  float b4[4];
#pragma unroll
  for (int j = 0; j < 4; j++) b4[j] = bias[nbase + j * 16 + r15];
#pragma unroll
  for (int i = 0; i < 4; i++) {
    const int rb = mbase + i * 16 + khi * 4;
#pragma unroll
    for (int e = 0; e < 4; e++) {
      const int r = rb + e;
      if (r < NN) {
#pragma unroll
        for (int j = 0; j < 4; j++)
          hout[r * HID + nbase + j * 16 + r15] = f2bf(acc[i][j][e] + b4[j]);
      }
    }
  }
}

// ---------- GEMM: h_new = relu(h @ Wl + agg @ Wr + bl) (bf16 in/out) ----------
__global__ __launch_bounds__(256) void k_layer(const unsigned short* __restrict__ hp,
                                               const unsigned short* __restrict__ ag,
                                               const unsigned short* __restrict__ WtL,
                                               const unsigned short* __restrict__ WtR,
                                               const float* __restrict__ bias,
                                               unsigned short* __restrict__ hout) {
  const int lane = threadIdx.x & 63, w = threadIdx.x >> 6;
  const int wr = w >> 1, wc = w & 1;
  const int r15 = lane & 15, khi = lane >> 4;
  const int mbase = blockIdx.x * 128 + wr * 64, nbase = wc * 64;
  f32x4 acc[4][4] = {};
#pragma unroll
  for (int ph = 0; ph < 2; ++ph) {
    const unsigned short* A = ph ? ag : hp;
    const unsigned short* B = ph ? WtR : WtL;
#pragma unroll
    for (int ks = 0; ks < 4; ++ks) {
      const int kk = ks * 32 + khi * 8;
      bf16x8 af[4], bq[4];
#pragma unroll
      for (int i = 0; i < 4; i++) {
        int row = mbase + i * 16 + r15; row = row < NN ? row : NN - 1;
        af[i] = *(const bf16x8*)(A + row * HID + kk);
      }
#pragma unroll
      for (int j = 0; j < 4; j++) {
        int col = nbase + j * 16 + r15;
        bq[j] = *(const bf16x8*)(B + col * HID + kk);
      }
#pragma unroll
      for (int i = 0; i < 4; i++)
#pragma unroll
        for (int j = 0; j < 4; j++) acc[i][j] = mfma(af[i], bq[j], acc[i][j]);
    }
  }
  float b4[4];
#pragma unroll
  for (int j = 0; j < 4; j++) b4[j] = bias[nbase + j * 16 + r15];
#pragma unroll
  for (int i = 0; i < 4; i++) {
    const int rb = mbase + i * 16 + khi * 4;
#pragma unroll
    for (int e = 0; e < 4; e++) {
      const int r = rb + e;
      if (r < NN) {
#pragma unroll
        for (int j = 0; j < 4; j++) {
          float v = acc[i][j][e] + b4[j];
          v = fmaxf(v, 0.f);
          hout[r * HID + nbase + j * 16 + r15] = f2bf(v);
        }
      }
    }
  }
}

// ---------- classifier: out = relu((h1+h2+h3)@Wc1+bc1)@Wc2+bc2 ----------
__global__ __launch_bounds__(256) void k_cls(const unsigned short* __restrict__ h1,
                                             const unsigned short* __restrict__ h2,
                                             const unsigned short* __restrict__ h3,
                                             const unsigned short* __restrict__ WtC1,
                                             const float* __restrict__ bc1,
                                             const unsigned short* __restrict__ WtC2,
                                             const float* __restrict__ bc2,
                                             float* __restrict__ out) {
  __shared__ unsigned short hc[128 * 136];  // padded row stride 136 (272B = 17*16B)
  const int lane = threadIdx.x & 63, w = threadIdx.x >> 6;
  const int wr = w >> 1, wc = w & 1;
  const int r15 = lane & 15, khi = lane >> 4;
  const int mbase = blockIdx.x * 128 + wr * 64, nbase = wc * 64;
  // stage 1: hc = relu((h1+h2+h3) @ Wc1 + bc1)
  {
    f32x4 acc[4][4] = {};
#pragma unroll
    for (int ks = 0; ks < 4; ++ks) {
      const int kk = ks * 32 + khi * 8;
      bf16x8 af[4], bq[4];
#pragma unroll
      for (int i = 0; i < 4; i++) {
        int row = mbase + i * 16 + r15; row = row < NN ? row : NN - 1;
        i32x4 u = *(const i32x4*)(h1 + row * HID + kk);
        i32x4 v = *(const i32x4*)(h2 + row * HID + kk);
        i32x4 q = *(const i32x4*)(h3 + row * HID + kk);
        i32x4 t;
#pragma unroll
        for (int c = 0; c < 4; c++) {
          unsigned uu = u[c], vv = v[c], qq = q[c];
          t[c] = pack2(bflo(uu) + bflo(vv) + bflo(qq), bfhi(uu) + bfhi(vv) + bfhi(qq));
        }
        af[i] = __builtin_bit_cast(bf16x8, t);
      }
#pragma unroll
      for (int j = 0; j < 4; j++) {
        int col = nbase + j * 16 + r15;
        bq[j] = *(const bf16x8*)(WtC1 + col * HID + kk);
      }
#pragma unroll
      for (int i = 0; i < 4; i++)
#pragma unroll
        for (int j = 0; j < 4; j++) acc[i][j] = mfma(af[i], bq[j], acc[i][j]);
    }
    float b4[4];
#pragma unroll
    for (int j = 0; j < 4; j++) b4[j] = bc1[nbase + j * 16 + r15];
#pragma unroll
    for (int i = 0; i < 4; i++) {
      const int rT = wr * 64 + i * 16 + khi * 4;
#pragma unroll
      for (int e = 0; e < 4; e++) {
#pragma unroll
        for (int j = 0; j < 4; j++) {
          float v = fmaxf(acc[i][j][e] + b4[j], 0.f);
          hc[(rT + e) * 136 + nbase + j * 16 + r15] = f2bf(v);
        }
      }
    }
  }
  __syncthreads();
  // stage 2: out = hc @ Wc2 + bc2  (each wave: 32 rows x 48 cols, store cols<40)
  {
    f32x4 a2[2][3] = {};
#pragma unroll
    for (int ks = 0; ks < 4; ++ks) {
      const int kk = ks * 32 + khi * 8;
      bf16x8 af[2], bq[3];
#pragma unroll
      for (int i = 0; i < 2; i++) {
        int rT = w * 32 + i * 16 + r15;
        af[i] = *(const bf16x8*)&hc[rT * 136 + kk];
      }
#pragma unroll
      for (int j = 0; j < 3; j++) {
        int col = j * 16 + r15;
        bq[j] = *(const bf16x8*)(WtC2 + col * HID + kk);
      }
#pragma unroll
      for (int i = 0; i < 2; i++)
#pragma unroll
        for (int j = 0; j < 3; j++) a2[i][j] = mfma(af[i], bq[j], a2[i][j]);
    }
#pragma unroll
    for (int j = 0; j < 3; j++) {
      const int col = j * 16 + r15;
      const float b = (col < OUTD) ? bc2[col] : 0.f;
#pragma unroll
      for (int i = 0; i < 2; i++) {
        const int rT = w * 32 + i * 16 + khi * 4;
#pragma unroll
        for (int e = 0; e < 4; e++) {
          const int gr = blockIdx.x * 128 + rT + e;
          if (gr < NN && col < OUTD) out[gr * OUTD + col] = a2[i][j][e] + b;
        }
      }
    }
  }
}

// ---------- launch ----------
extern "C" void kernel_launch(void* const* d_in, const int* in_sizes, int n_in,
                              void* d_out, int out_size, void* d_ws, size_t ws_size,
                              hipStream_t stream) {
  (void)in_sizes; (void)n_in; (void)out_size; (void)ws_size;
  const float* x   = (const float*)d_in[0];
  const int*   ei  = (const int*)d_in[1];
  const float* Win = (const float*)d_in[2];
  const float* bin = (const float*)d_in[3];
  const float* Wl  = (const float*)d_in[4];
  const float* Wr  = (const float*)d_in[5];
  const float* bl  = (const float*)d_in[6];
  const float* Wc1 = (const float*)d_in[7];
  const float* bc1 = (const float*)d_in[8];
  const float* Wc2 = (const float*)d_in[9];
  const float* bc2 = (const float*)d_in[10];
  float* out = (float*)d_out;

  char* ws = (char*)d_ws;
  size_t off = 0;
  auto take = [&](size_t bytes) -> char* {
    char* p = ws + off; off = (off + bytes + 255) & ~(size_t)255; return p;
  };
  int* deg        = (int*)take((size_t)NN * 4);
  int* offs       = (int*)take((size_t)(NN + 1) * 4);
  int* pos        = (int*)take((size_t)NE * 4);
  int* bsum       = (int*)take(256 * 4);
  int* bexcl      = (int*)take(256 * 4);
  float* dinv     = (float*)take((size_t)NN * 4);
  int* csr        = (int*)take((size_t)NE * 4);
  unsigned short* wt  = (unsigned short*)take((size_t)(8 * 16384 + 48 * 128) * 2);
  unsigned short* h0  = (unsigned short*)take((size_t)NN * HID * 2);
  unsigned short* h1  = (unsigned short*)take((size_t)NN * HID * 2);
  unsigned short* h2  = (unsigned short*)take((size_t)NN * HID * 2);
  unsigned short* h3  = (unsigned short*)take((size_t)NN * HID * 2);
  unsigned short* agg = (unsigned short*)take((size_t)NN * HID * 2);

  const int* esrc = ei;
  const int* edst = ei + NE;

  hipMemsetAsync(deg, 0, (size_t)NN * 4, stream);
  k_deg<<<(NE + 255) / 256, 256, 0, stream>>>(edst, deg, pos);
  k_blocksum<<<NBLK, 256, 0, stream>>>(deg, bsum);
  k_scanb<<<1, 256, 0, stream>>>(bsum, bexcl);
  k_scan3<<<NBLK, 256, 0, stream>>>(deg, bexcl, offs, dinv);
  k_fill<<<(NE + 255) / 256, 256, 0, stream>>>(esrc, edst, pos, offs, csr);
  k_prep<<<(8 * 16384 + 48 * 128 + 255) / 256, 256, 0, stream>>>(Win, Wl, Wr, Wc1, Wc2, wt);
  k_lin_in<<<(NN + 127) / 128, 256, 0, stream>>>(x, wt, bin, h0);

  unsigned short* hs[4] = {h0, h1, h2, h3};
  for (int i = 0; i < 3; i++) {
    k_agg<<<2048, 256, 0, stream>>>(hs[i], csr, offs, dinv, agg);
    k_layer<<<(NN + 127) / 128, 256, 0, stream>>>(hs[i], agg, wt + (1 + i) * 16384,
                                                  wt + (4 + i) * 16384, bl + i * HID, hs[i + 1]);
  }
  k_cls<<<(NN + 127) / 128, 256, 0, stream>>>(h1, h2, h3, wt + 7 * 16384, bc1,
                                              wt + 8 * 16384, bc2, out);
}

// Round 6
// 254.982 us; speedup vs baseline: 1.1382x; 1.1382x over previous
//
#include <hip/hip_runtime.h>

#define NN   50000
#define NE   800000
#define HID  128
#define OUTD 40
#define NBLK 196  // ceil(NN/256)

typedef float f32x4  __attribute__((ext_vector_type(4)));
typedef int   i32x4  __attribute__((ext_vector_type(4)));
typedef short bf16x8 __attribute__((ext_vector_type(8)));

// ---------- helpers ----------
__device__ __forceinline__ f32x4 mfma(bf16x8 a, bf16x8 b, f32x4 c) {
  return __builtin_amdgcn_mfma_f32_16x16x32_bf16(a, b, c, 0, 0, 0);
}
__device__ __forceinline__ unsigned short f2bf(float f) {
  unsigned u = __builtin_bit_cast(unsigned, f);
  u += 0x7fffu + ((u >> 16) & 1u);
  return (unsigned short)(u >> 16);
}
__device__ __forceinline__ unsigned pack2(float lo, float hi) {
  return (unsigned)f2bf(lo) | ((unsigned)f2bf(hi) << 16);
}
__device__ __forceinline__ float bflo(unsigned v){ return __builtin_bit_cast(float, v << 16); }
__device__ __forceinline__ float bfhi(unsigned v){ return __builtin_bit_cast(float, v & 0xffff0000u); }

// ---------- CSR build ----------
// k_deg: count in-degree AND record each edge's rank within its dst bucket.
__global__ void k_deg(const int* __restrict__ dst, int* __restrict__ deg,
                      int* __restrict__ pos) {
  int i = blockIdx.x * blockDim.x + threadIdx.x;
  if (i < NE) pos[i] = atomicAdd(&deg[dst[i]], 1);
}

__global__ void k_blocksum(const int* __restrict__ deg, int* __restrict__ bsum) {
  __shared__ int s[256];
  int t = threadIdx.x, i = blockIdx.x * 256 + t;
  s[t] = (i < NN) ? deg[i] : 0;
  __syncthreads();
  for (int o = 128; o > 0; o >>= 1) { if (t < o) s[t] += s[t + o]; __syncthreads(); }
  if (t == 0) bsum[blockIdx.x] = s[0];
}

// fused: per-block exclusive base (reduce bsum[0..blockIdx)) + local scan
__global__ void k_scan3(const int* __restrict__ deg, const int* __restrict__ bsum,
                        int* __restrict__ offs, float* __restrict__ dinv) {
  __shared__ int sb[256];
  __shared__ int s[256];
  int t = threadIdx.x, i = blockIdx.x * 256 + t;
  sb[t] = (t < NBLK && t < blockIdx.x) ? bsum[t] : 0;
  int v = (i < NN) ? deg[i] : 0;
  s[t] = v;
  __syncthreads();
  for (int o = 128; o > 0; o >>= 1) { if (t < o) sb[t] += sb[t + o]; __syncthreads(); }
  for (int o = 1; o < 256; o <<= 1) {
    int x = (t >= o) ? s[t - o] : 0;
    __syncthreads(); s[t] += x; __syncthreads();
  }
  int off = sb[0] + s[t] - v;  // exclusive within-array offset
  if (i < NN) {
    offs[i] = off;
    dinv[i] = 1.0f / (float)(v > 0 ? v : 1);
  }
  if (i == 0) offs[NN] = NE;
}

// no atomics: position precomputed in k_deg
__global__ void k_fill(const int* __restrict__ src, const int* __restrict__ dst,
                       const int* __restrict__ pos, const int* __restrict__ offs,
                       int* __restrict__ csr) {
  int i = blockIdx.x * blockDim.x + threadIdx.x;
  if (i < NE) {
    csr[offs[dst[i]] + pos[i]] = src[i];
  }
}

// ---------- weight prep: transpose + bf16 cast into ws; also zeros deg ----------
// wt layout: m=0 WtIn, m=1..3 WtL[i], m=4..6 WtR[i], m=7 WtC1, then WtC2 [48][128]
__global__ void k_prep(const float* __restrict__ Win, const float* __restrict__ Wl,
                       const float* __restrict__ Wr, const float* __restrict__ Wc1,
                       const float* __restrict__ Wc2, unsigned short* __restrict__ wt,
                       int* __restrict__ deg) {
  int idx = blockIdx.x * 256 + threadIdx.x;
  if (idx < NN) deg[idx] = 0;  // fold the memset dispatch in here
  const int NMAIN = 8 * 16384;
  if (idx >= NMAIN + 48 * 128) return;
  float v;
  if (idx < NMAIN) {
    int m = idx >> 14, rem = idx & 16383;
    int n = rem >> 7, k = rem & 127;
    const float* s;
    if (m == 0) s = Win;
    else if (m <= 3) s = Wl + (m - 1) * 16384;
    else if (m <= 6) s = Wr + (m - 4) * 16384;
    else s = Wc1;
    v = s[k * 128 + n];
  } else {
    int rem = idx - NMAIN;
    int n = rem >> 7, k = rem & 127;
    v = (n < OUTD) ? Wc2[k * OUTD + n] : 0.f;
  }
  wt[idx] = f2bf(v);
}

// ---------- aggregation: half-wave per row (8B/lane), 8 rows/iter ----------
// One VMEM instruction fetches 2 rows (lanes 0-31 -> row a, lanes 32-63 -> row b).
// csr indices for the NEXT iteration are prefetched while the current h-row
// loads are in flight (overlaps the two chained latencies).
__global__ __launch_bounds__(256) void k_agg(const unsigned short* __restrict__ h,
                                             const int* __restrict__ csr,
                                             const int* __restrict__ offs,
                                             const float* __restrict__ dinv,
                                             unsigned short* __restrict__ agg) {
  const int lane = threadIdx.x & 63;
  const int l31 = lane & 31;
  const int hi = lane >> 5;  // which row of the pair this half-wave reads
  int gw = (blockIdx.x * blockDim.x + threadIdx.x) >> 6;
  int nw = (gridDim.x * blockDim.x) >> 6;
  const uint2* h2 = (const uint2*)h;  // row stride = 32 uint2 (256B)
  uint2* ag2 = (uint2*)agg;
  for (int n = gw; n < NN; n += nw) {
    int s = offs[n], e = offs[n + 1];
    float a0 = 0, a1 = 0, a2 = 0, a3 = 0;
    float b0 = 0, b1 = 0, b2 = 0, b3 = 0;
    float c0 = 0, c1 = 0, c2 = 0, c3 = 0;
    float d0 = 0, d1 = 0, d2 = 0, d3 = 0;
    int k = s;
    int r0, r1, r2, r3;
    bool have = (k + 8 <= e);
    if (have) {
      r0 = csr[k + 0 + hi]; r1 = csr[k + 2 + hi];
      r2 = csr[k + 4 + hi]; r3 = csr[k + 6 + hi];
    }
    while (have) {
      uint2 v0 = h2[r0 * 32 + l31];
      uint2 v1 = h2[r1 * 32 + l31];
      uint2 v2 = h2[r2 * 32 + l31];
      uint2 v3 = h2[r3 * 32 + l31];
      k += 8;
      have = (k + 8 <= e);
      if (have) {  // prefetch next indices while v0..v3 are in flight
        r0 = csr[k + 0 + hi]; r1 = csr[k + 2 + hi];
        r2 = csr[k + 4 + hi]; r3 = csr[k + 6 + hi];
      }
      a0 += bflo(v0.x); a1 += bfhi(v0.x); a2 += bflo(v0.y); a3 += bfhi(v0.y);
      b0 += bflo(v1.x); b1 += bfhi(v1.x); b2 += bflo(v1.y); b3 += bfhi(v1.y);
      c0 += bflo(v2.x); c1 += bfhi(v2.x); c2 += bflo(v2.y); c3 += bfhi(v2.y);
      d0 += bflo(v3.x); d1 += bfhi(v3.x); d2 += bflo(v3.y); d3 += bfhi(v3.y);
    }
    for (; k + 2 <= e; k += 2) {
      int r = csr[k + hi];
      uint2 v = h2[r * 32 + l31];
      a0 += bflo(v.x); a1 += bfhi(v.x); a2 += bflo(v.y); a3 += bfhi(v.y);
    }
    if (k < e) {  // odd last row: both halves load it, only low half accumulates
      int r = csr[k];
      uint2 v = h2[r * 32 + l31];
      if (hi == 0) {
        a0 += bflo(v.x); a1 += bfhi(v.x); a2 += bflo(v.y); a3 += bfhi(v.y);
      }
    }
    float s0 = a0 + b0 + c0 + d0, s1 = a1 + b1 + c1 + d1;
    float s2 = a2 + b2 + c2 + d2, s3 = a3 + b3 + c3 + d3;
    s0 += __shfl_xor(s0, 32); s1 += __shfl_xor(s1, 32);
    s2 += __shfl_xor(s2, 32); s3 += __shfl_xor(s3, 32);
    float di = dinv[n];
    if (hi == 0) {
      uint2 o;
      o.x = pack2(s0 * di, s1 * di);
      o.y = pack2(s2 * di, s3 * di);
      ag2[n * 32 + l31] = o;
    }
  }
}

// ---------- GEMM: h0 = x @ W_in + b_in (x fp32, out bf16) ----------
__global__ __launch_bounds__(256) void k_lin_in(const float* __restrict__ x,
                                                const unsigned short* __restrict__ Wt,
                                                const float* __restrict__ bias,
                                                unsigned short* __restrict__ hout) {
  const int lane = threadIdx.x & 63, w = threadIdx.x >> 6;
  const int wr = w >> 1, wc = w & 1;
  const int r15 = lane & 15, khi = lane >> 4;
  const int mbase = blockIdx.x * 128 + wr * 64, nbase = wc * 64;
  f32x4 acc[4][4] = {};
#pragma unroll
  for (int ks = 0; ks < 4; ++ks) {
    const int kk = ks * 32 + khi * 8;
    bf16x8 af[4], bq[4];
#pragma unroll
    for (int i = 0; i < 4; i++) {
      int row = mbase + i * 16 + r15; row = row < NN ? row : NN - 1;
      const f32x4* p = (const f32x4*)(x + row * HID + kk);
      f32x4 lo = p[0], hi = p[1];
      i32x4 t;
      t[0] = pack2(lo[0], lo[1]); t[1] = pack2(lo[2], lo[3]);
      t[2] = pack2(hi[0], hi[1]); t[3] = pack2(hi[2], hi[3]);
      af[i] = __builtin_bit_cast(bf16x8, t);
    }
#pragma unroll
    for (int j = 0; j < 4; j++) {
      int col = nbase + j * 16 + r15;
      bq[j] = *(const bf16x8*)(Wt + col * HID + kk);
    }
#pragma unroll
    for (int i = 0; i < 4; i++)
#pragma unroll
      for (int j = 0; j < 4; j++) acc[i][j] = mfma(af[i], bq[j], acc[i][j]);
  }
  float b4[4];
#pragma unroll
  for (int j = 0; j < 4; j++) b4[j] = bias[nbase + j * 16 + r15];
#pragma unroll
  for (int i = 0; i < 4; i++) {
    const int rb = mbase + i * 16 + khi * 4;
#pragma unroll
    for (int e = 0; e < 4; e++) {
      const int r = rb + e;
      if (r < NN) {
#pragma unroll
        for (int j = 0; j < 4; j++)
          hout[r * HID + nbase + j * 16 + r15] = f2bf(acc[i][j][e] + b4[j]);
      }
    }
  }
}

// ---------- GEMM: h_new = relu(h @ Wl + agg @ Wr + bl) (bf16 in/out) ----------
__global__ __launch_bounds__(256) void k_layer(const unsigned short* __restrict__ hp,
                                               const unsigned short* __restrict__ ag,
                                               const unsigned short* __restrict__ WtL,
                                               const unsigned short* __restrict__ WtR,
                                               const float* __restrict__ bias,
                                               unsigned short* __restrict__ hout) {
  const int lane = threadIdx.x & 63, w = threadIdx.x >> 6;
  const int wr = w >> 1, wc = w & 1;
  const int r15 = lane & 15, khi = lane >> 4;
  const int mbase = blockIdx.x * 128 + wr * 64, nbase = wc * 64;
  f32x4 acc[4][4] = {};
#pragma unroll
  for (int ph = 0; ph < 2; ++ph) {
    const unsigned short* A = ph ? ag : hp;
    const unsigned short* B = ph ? WtR : WtL;
#pragma unroll
    for (int ks = 0; ks < 4; ++ks) {
      const int kk = ks * 32 + khi * 8;
      bf16x8 af[4], bq[4];
#pragma unroll
      for (int i = 0; i < 4; i++) {
        int row = mbase + i * 16 + r15; row = row < NN ? row : NN - 1;
        af[i] = *(const bf16x8*)(A + row * HID + kk);
      }
#pragma unroll
      for (int j = 0; j < 4; j++) {
        int col = nbase + j * 16 + r15;
        bq[j] = *(const bf16x8*)(B + col * HID + kk);
      }
#pragma unroll
      for (int i = 0; i < 4; i++)
#pragma unroll
        for (int j = 0; j < 4; j++) acc[i][j] = mfma(af[i], bq[j], acc[i][j]);
    }
  }
  float b4[4];
#pragma unroll
  for (int j = 0; j < 4; j++) b4[j] = bias[nbase + j * 16 + r15];
#pragma unroll
  for (int i = 0; i < 4; i++) {
    const int rb = mbase + i * 16 + khi * 4;
#pragma unroll
    for (int e = 0; e < 4; e++) {
      const int r = rb + e;
      if (r < NN) {
#pragma unroll
        for (int j = 0; j < 4; j++) {
          float v = acc[i][j][e] + b4[j];
          v = fmaxf(v, 0.f);
          hout[r * HID + nbase + j * 16 + r15] = f2bf(v);
        }
      }
    }
  }
}

// ---------- classifier: out = relu((h1+h2+h3)@Wc1+bc1)@Wc2+bc2 ----------
__global__ __launch_bounds__(256) void k_cls(const unsigned short* __restrict__ h1,
                                             const unsigned short* __restrict__ h2,
                                             const unsigned short* __restrict__ h3,
                                             const unsigned short* __restrict__ WtC1,
                                             const float* __restrict__ bc1,
                                             const unsigned short* __restrict__ WtC2,
                                             const float* __restrict__ bc2,
                                             float* __restrict__ out) {
  __shared__ unsigned short hc[128 * 136];  // padded row stride 136 (272B = 17*16B)
  const int lane = threadIdx.x & 63, w = threadIdx.x >> 6;
  const int wr = w >> 1, wc = w & 1;
  const int r15 = lane & 15, khi = lane >> 4;
  const int mbase = blockIdx.x * 128 + wr * 64, nbase = wc * 64;
  // stage 1: hc = relu((h1+h2+h3) @ Wc1 + bc1)
  {
    f32x4 acc[4][4] = {};
#pragma unroll
    for (int ks = 0; ks < 4; ++ks) {
      const int kk = ks * 32 + khi * 8;
      bf16x8 af[4], bq[4];
#pragma unroll
      for (int i = 0; i < 4; i++) {
        int row = mbase + i * 16 + r15; row = row < NN ? row : NN - 1;
        i32x4 u = *(const i32x4*)(h1 + row * HID + kk);
        i32x4 v = *(const i32x4*)(h2 + row * HID + kk);
        i32x4 q = *(const i32x4*)(h3 + row * HID + kk);
        i32x4 t;
#pragma unroll
        for (int c = 0; c < 4; c++) {
          unsigned uu = u[c], vv = v[c], qq = q[c];
          t[c] = pack2(bflo(uu) + bflo(vv) + bflo(qq), bfhi(uu) + bfhi(vv) + bfhi(qq));
        }
        af[i] = __builtin_bit_cast(bf16x8, t);
      }
#pragma unroll
      for (int j = 0; j < 4; j++) {
        int col = nbase + j * 16 + r15;
        bq[j] = *(const bf16x8*)(WtC1 + col * HID + kk);
      }
#pragma unroll
      for (int i = 0; i < 4; i++)
#pragma unroll
        for (int j = 0; j < 4; j++) acc[i][j] = mfma(af[i], bq[j], acc[i][j]);
    }
    float b4[4];
#pragma unroll
    for (int j = 0; j < 4; j++) b4[j] = bc1[nbase + j * 16 + r15];
#pragma unroll
    for (int i = 0; i < 4; i++) {
      const int rT = wr * 64 + i * 16 + khi * 4;
#pragma unroll
      for (int e = 0; e < 4; e++) {
#pragma unroll
        for (int j = 0; j < 4; j++) {
          float v = fmaxf(acc[i][j][e] + b4[j], 0.f);
          hc[(rT + e) * 136 + nbase + j * 16 + r15] = f2bf(v);
        }
      }
    }
  }
  __syncthreads();
  // stage 2: out = hc @ Wc2 + bc2  (each wave: 32 rows x 48 cols, store cols<40)
  {
    f32x4 a2[2][3] = {};
#pragma unroll
    for (int ks = 0; ks < 4; ++ks) {
      const int kk = ks * 32 + khi * 8;
      bf16x8 af[2], bq[3];
#pragma unroll
      for (int i = 0; i < 2; i++) {
        int rT = w * 32 + i * 16 + r15;
        af[i] = *(const bf16x8*)&hc[rT * 136 + kk];
      }
#pragma unroll
      for (int j = 0; j < 3; j++) {
        int col = j * 16 + r15;
        bq[j] = *(const bf16x8*)(WtC2 + col * HID + kk);
      }
#pragma unroll
      for (int i = 0; i < 2; i++)
#pragma unroll
        for (int j = 0; j < 3; j++) a2[i][j] = mfma(af[i], bq[j], a2[i][j]);
    }
#pragma unroll
    for (int j = 0; j < 3; j++) {
      const int col = j * 16 + r15;
      const float b = (col < OUTD) ? bc2[col] : 0.f;
#pragma unroll
      for (int i = 0; i < 2; i++) {
        const int rT = w * 32 + i * 16 + khi * 4;
#pragma unroll
        for (int e = 0; e < 4; e++) {
          const int gr = blockIdx.x * 128 + rT + e;
          if (gr < NN && col < OUTD) out[gr * OUTD + col] = a2[i][j][e] + b;
        }
      }
    }
  }
}

// ---------- launch ----------
extern "C" void kernel_launch(void* const* d_in, const int* in_sizes, int n_in,
                              void* d_out, int out_size, void* d_ws, size_t ws_size,
                              hipStream_t stream) {
  (void)in_sizes; (void)n_in; (void)out_size; (void)ws_size;
  const float* x   = (const float*)d_in[0];
  const int*   ei  = (const int*)d_in[1];
  const float* Win = (const float*)d_in[2];
  const float* bin = (const float*)d_in[3];
  const float* Wl  = (const float*)d_in[4];
  const float* Wr  = (const float*)d_in[5];
  const float* bl  = (const float*)d_in[6];
  const float* Wc1 = (const float*)d_in[7];
  const float* bc1 = (const float*)d_in[8];
  const float* Wc2 = (const float*)d_in[9];
  const float* bc2 = (const float*)d_in[10];
  float* out = (float*)d_out;

  char* ws = (char*)d_ws;
  size_t off = 0;
  auto take = [&](size_t bytes) -> char* {
    char* p = ws + off; off = (off + bytes + 255) & ~(size_t)255; return p;
  };
  int* deg        = (int*)take((size_t)NN * 4);
  int* offs       = (int*)take((size_t)(NN + 1) * 4);
  int* pos        = (int*)take((size_t)NE * 4);
  int* bsum       = (int*)take(256 * 4);
  float* dinv     = (float*)take((size_t)NN * 4);
  int* csr        = (int*)take((size_t)NE * 4);
  unsigned short* wt  = (unsigned short*)take((size_t)(8 * 16384 + 48 * 128) * 2);
  unsigned short* h0  = (unsigned short*)take((size_t)NN * HID * 2);
  unsigned short* h1  = (unsigned short*)take((size_t)NN * HID * 2);
  unsigned short* h2  = (unsigned short*)take((size_t)NN * HID * 2);
  unsigned short* h3  = (unsigned short*)take((size_t)NN * HID * 2);
  unsigned short* agg = (unsigned short*)take((size_t)NN * HID * 2);

  const int* esrc = ei;
  const int* edst = ei + NE;

  k_prep<<<(8 * 16384 + 48 * 128 + 255) / 256, 256, 0, stream>>>(Win, Wl, Wr, Wc1, Wc2, wt, deg);
  k_deg<<<(NE + 255) / 256, 256, 0, stream>>>(edst, deg, pos);
  k_blocksum<<<NBLK, 256, 0, stream>>>(deg, bsum);
  k_scan3<<<NBLK, 256, 0, stream>>>(deg, bsum, offs, dinv);
  k_fill<<<(NE + 255) / 256, 256, 0, stream>>>(esrc, edst, pos, offs, csr);
  k_lin_in<<<(NN + 127) / 128, 256, 0, stream>>>(x, wt, bin, h0);

  unsigned short* hs[4] = {h0, h1, h2, h3};
  for (int i = 0; i < 3; i++) {
    k_agg<<<2048, 256, 0, stream>>>(hs[i], csr, offs, dinv, agg);
    k_layer<<<(NN + 127) / 128, 256, 0, stream>>>(hs[i], agg, wt + (1 + i) * 16384,
                                                  wt + (4 + i) * 16384, bl + i * HID, hs[i + 1]);
  }
  k_cls<<<(NN + 127) / 128, 256, 0, stream>>>(h1, h2, h3, wt + 7 * 16384, bc1,
                                              wt + 8 * 16384, bc2, out);
}